// Round 5
// baseline (582.521 us; speedup 1.0000x reference)
//
#include <hip/hip_runtime.h>

#define BB 128
#define TT 512
#define CC 128

typedef short short8 __attribute__((ext_vector_type(8)));
typedef float f32x4  __attribute__((ext_vector_type(4)));

__device__ __forceinline__ unsigned pk_trunc(float a, float b) {
    // lo16 = trunc-bf16(a), hi16 = trunc-bf16(b); single v_perm
    return __builtin_amdgcn_perm(__float_as_uint(a), __float_as_uint(b), 0x03020706u);
}
__device__ __forceinline__ unsigned short f2bf(float f) {   // RNE (A setup only)
    unsigned u = __float_as_uint(f);
    u += 0x7fffu + ((u >> 16) & 1u);
    return (unsigned short)(u >> 16);
}
__device__ __forceinline__ float lo16f(unsigned u) { return __uint_as_float(u << 16); }
__device__ __forceinline__ float hi16f(unsigned u) { return __uint_as_float(u & 0xffff0000u); }

#define MFMA16(A, B, C) __builtin_amdgcn_mfma_f32_16x16x32_bf16((A), (B), (C), 0, 0, 0)

// One scan step, fully in registers. MACRO (not lambda): R4's lambda was not
// inlined -> captured arrays (ps/Af/pf) went to scratch (VGPR=164 < live set
// ~300, 2355 cyc/step). Macro guarantees inline + static indexing.
// Semantics (verified R0/R4): RN at t%4==0 (pend=1/state[0], lacc+=log);
// AP at t%4==1 (apply pend to new state); keep-old when mask<=0.
#define DOSTEP(t_, pf_, pm_) do {                                              \
    const int t__ = (t_);                                                      \
    const float mm = (pm_);                                                    \
    float e[8][4];                                                             \
    _Pragma("unroll")                                                          \
    for (int i = 0; i < 8; ++i) {                                              \
        e[i][0] = __expf(pf_[i].x * mm); e[i][1] = __expf(pf_[i].y * mm);      \
        e[i][2] = __expf(pf_[i].z * mm); e[i][3] = __expf(pf_[i].w * mm);      \
    }                                                                          \
    const int tn = t__ + 2;                                                    \
    if (tn < TT) {                                                             \
        const float* r__ = yb + (size_t)tn * CC;                               \
        _Pragma("unroll")                                                      \
        for (int i = 0; i < 8; ++i) pf_[i] = *(const float4*)(r__ + offc[i]);  \
        (pm_) = mrow[tn];                                                      \
    }                                                                          \
    short8 Bf[4];                                                              \
    _Pragma("unroll")                                                          \
    for (int kt = 0; kt < 4; ++kt) {                                           \
        union { unsigned u[4]; short8 s; } bu;                                 \
        bu.u[0] = ps[4 * kt + 0]; bu.u[1] = ps[4 * kt + 1];                    \
        bu.u[2] = ps[4 * kt + 2]; bu.u[3] = ps[4 * kt + 3];                    \
        Bf[kt] = bu.s;                                                         \
    }                                                                          \
    f32x4 acc[8];                                                              \
    _Pragma("unroll")                                                          \
    for (int nt = 0; nt < 8; ++nt) { f32x4 z = {0.f,0.f,0.f,0.f}; acc[nt] = z; } \
    _Pragma("unroll")                                                          \
    for (int kt = 0; kt < 4; ++kt) {                                           \
        _Pragma("unroll")                                                      \
        for (int nt = 0; nt < 8; ++nt)                                         \
            acc[nt] = MFMA16(Af[nt][kt], Bf[kt], acc[nt]);                     \
    }                                                                          \
    const bool ap = (t__ & 3) == 1;                                            \
    float val[8][4];                                                           \
    _Pragma("unroll")                                                          \
    for (int nt = 0; nt < 8; ++nt) {                                           \
        val[nt][0] = acc[nt][0] * e[nt][0]; val[nt][1] = acc[nt][1] * e[nt][1];\
        val[nt][2] = acc[nt][2] * e[nt][2]; val[nt][3] = acc[nt][3] * e[nt][3];\
        if (ap) {                                                              \
            val[nt][0] *= pend; val[nt][1] *= pend;                            \
            val[nt][2] *= pend; val[nt][3] *= pend;                            \
        }                                                                      \
    }                                                                          \
    unsigned nps[16];                                                          \
    _Pragma("unroll")                                                          \
    for (int nt = 0; nt < 8; ++nt) {                                           \
        const int kt = nt & 3, hh = nt >> 2;                                   \
        nps[kt * 4 + 2 * hh + 0] = pk_trunc(val[nt][0], val[nt][1]);           \
        nps[kt * 4 + 2 * hh + 1] = pk_trunc(val[nt][2], val[nt][3]);           \
    }                                                                          \
    if (__ballot(mm <= 0.f)) {              /* rare keep-old (never hit) */    \
        const float pe = ap ? pend : 1.f;                                      \
        _Pragma("unroll")                                                      \
        for (int p2 = 0; p2 < 16; ++p2) {                                      \
            unsigned kept = pk_trunc(lo16f(ps[p2]) * pe, hi16f(ps[p2]) * pe);  \
            nps[p2] = (mm <= 0.f) ? kept : nps[p2];                            \
        }                                                                      \
    }                                                                          \
    _Pragma("unroll")                                                          \
    for (int p2 = 0; p2 < 16; ++p2) ps[p2] = nps[p2];                          \
    if (ap) pend = 1.f;                                                        \
    if ((t__ & 3) == 0) {                   /* RN */                           \
        float s2 = lo16f(ps[0]);                                               \
        float bc = __shfl(s2, bq, 64);      /* channel 0 lives at q=0 lanes */ \
        pend = __builtin_amdgcn_rcpf(bc);                                      \
        lacc += __logf(bc);                                                    \
    }                                                                          \
} while (0)

// ---------------------------------------------------------------------------
// One fused kernel, 256 threads per block.
// Blocks 0..7  : scan group g — SINGLE register-resident wave (waves 1..3 exit).
//                sigma-permuted A layout (R0/R4-verified): MFMA output channels
//                per lane == next step's B-frag channels; state stays in ps[16].
//                No LDS, no barriers. E self-loaded (8 float4/lane at sigma
//                offsets), depth-2 prefetch; exp on TRANS pipe under MFMA.
// Blocks 8..135: real-path score, 4 waves x 128 rows; atomicAdd(-score).
// ---------------------------------------------------------------------------
__global__ __launch_bounds__(256, 1) void crf_all(
    const float* __restrict__ y_true, const float* __restrict__ y_pred,
    const float* __restrict__ mask, const float* __restrict__ trans,
    float* __restrict__ out)
{
    const int tid  = threadIdx.x;
    const int lane = tid & 63;
    const int w    = tid >> 6;

    if (blockIdx.x >= 8) {
        // ===================== real path (verified core, 4x128) =============
        const int rb  = blockIdx.x - 8;
        const int ts  = w * 128;
        const int te  = min(ts + 128, TT - 1);
        const float* yt_b = y_true + (size_t)rb * TT * CC;
        const float* yp_b = y_pred + (size_t)rb * TT * CC;
        const float* m_b  = mask + (size_t)rb * TT;

        float em = 0.f, tr = 0.f;
        int lprev = 0; float mprev = 0.f;
        const float* ytr = yt_b + ts * CC;
        const float* ypr = yp_b + ts * CC;
        float cyt0 = ytr[lane], cyt1 = ytr[lane + 64];
        float cyp0 = ypr[lane], cyp1 = ypr[lane + 64];
        float cm = m_b[ts];
        for (int t = ts; t <= te; ++t) {
            float nyt0 = 0.f, nyt1 = 0.f, nyp0 = 0.f, nyp1 = 0.f, nm = 0.f;
            if (t < te) {
                const float* ytn = yt_b + (t + 1) * CC;
                const float* ypn = yp_b + (t + 1) * CC;
                nyt0 = ytn[lane]; nyt1 = ytn[lane + 64];
                nyp0 = ypn[lane]; nyp1 = ypn[lane + 64];
                nm = m_b[t + 1];
            }
            unsigned long long b0 = __ballot(cyt0 > 0.5f);
            unsigned long long b1 = __ballot(cyt1 > 0.5f);
            int l = b0 ? (__ffsll(b0) - 1) : (64 + __ffsll(b1) - 1);
            float v0 = __shfl(cyp0, l & 63);
            float v1 = __shfl(cyp1, l & 63);
            float v  = (l < 64) ? v0 : v1;
            if (lane == 0) {
                if (t < ts + 128) em += cm * cm * v;
                if (t > ts)       tr += mprev * cm * trans[lprev * CC + l];
            }
            lprev = l; mprev = cm;
            cyt0 = nyt0; cyt1 = nyt1; cyp0 = nyp0; cyp1 = nyp1; cm = nm;
        }
        if (lane == 0) atomicAdd(&out[rb], -(em + tr));
        return;
    }

    // ========================== scan blocks ==========================
    if (w != 0) return;                      // single-wave chain; free the SIMDs

    const int bq = lane & 15;
    const int q  = lane >> 4;
    const int g  = blockIdx.x;
    const float* yb   = y_pred + (size_t)(g * 16 + bq) * TT * CC;
    const float* mrow = mask + (size_t)(g * 16 + bq) * TT;

    // sigma-permuted E offsets: float4 i covers channels 32(i&3)+8q+4(i>>2)+{0..3}
    int offc[8];
    #pragma unroll
    for (int i = 0; i < 8; ++i) offc[i] = 32 * (i & 3) + 8 * q + 4 * (i >> 2);

    // A-frags with row-perm sigma (R0-verified): output layout == B-frag layout.
    short8 Af[8][4];
    #pragma unroll
    for (int nt = 0; nt < 8; ++nt) {
        const int j = 32 * (nt & 3) + 8 * (bq >> 2) + 4 * (nt >> 2) + (bq & 3);
        #pragma unroll
        for (int kt = 0; kt < 4; ++kt) {
            #pragma unroll
            for (int e = 0; e < 8; ++e)
                Af[nt][kt][e] = (short)f2bf(__expf(trans[(kt * 32 + q * 8 + e) * CC + j]));
        }
    }

    // t=0 init: ps[4kt+j] covers channels 32kt+8q+{2j,2j+1}.
    unsigned ps[16];
    {
        const float m0 = mrow[0];
        #pragma unroll
        for (int kt = 0; kt < 4; ++kt) {
            float4 g0 = *(const float4*)(yb + offc[kt]);        // e0..e3
            float4 g1 = *(const float4*)(yb + offc[4 + kt]);    // e4..e7
            ps[4 * kt + 0] = pk_trunc(__expf(g0.x * m0), __expf(g0.y * m0));
            ps[4 * kt + 1] = pk_trunc(__expf(g0.z * m0), __expf(g0.w * m0));
            ps[4 * kt + 2] = pk_trunc(__expf(g1.x * m0), __expf(g1.y * m0));
            ps[4 * kt + 3] = pk_trunc(__expf(g1.z * m0), __expf(g1.w * m0));
        }
    }

    // depth-2 E prefetch (named slots — static register indexing)
    float4 pfA[8], pfB[8]; float pmA, pmB;
    #pragma unroll
    for (int i = 0; i < 8; ++i) pfA[i] = *(const float4*)(yb + 1 * CC + offc[i]);
    pmA = mrow[1];
    #pragma unroll
    for (int i = 0; i < 8; ++i) pfB[i] = *(const float4*)(yb + 2 * CC + offc[i]);
    pmB = mrow[2];

    float lacc = 0.f, pend = 1.f;

    // steps 1..510 (odd -> slot A, even -> slot B)
    for (int t = 1; t <= 509; t += 2) {
        DOSTEP(t,     pfA, pmA);
        DOSTEP(t + 1, pfB, pmB);
    }

    // -------- step 511: final weighted sum (slot A; pend == 1, 511%4==3) ----
    {
        const float mm = pmA;
        float e[8][4];
        #pragma unroll
        for (int i = 0; i < 8; ++i) {
            e[i][0] = __expf(pfA[i].x * mm); e[i][1] = __expf(pfA[i].y * mm);
            e[i][2] = __expf(pfA[i].z * mm); e[i][3] = __expf(pfA[i].w * mm);
        }
        short8 Bf[4];
        #pragma unroll
        for (int kt = 0; kt < 4; ++kt) {
            union { unsigned u[4]; short8 s; } bu;
            bu.u[0] = ps[4 * kt + 0]; bu.u[1] = ps[4 * kt + 1];
            bu.u[2] = ps[4 * kt + 2]; bu.u[3] = ps[4 * kt + 3];
            Bf[kt] = bu.s;
        }
        f32x4 acc[8];
        #pragma unroll
        for (int nt = 0; nt < 8; ++nt) { f32x4 z = {0.f,0.f,0.f,0.f}; acc[nt] = z; }
        #pragma unroll
        for (int kt = 0; kt < 4; ++kt)
            #pragma unroll
            for (int nt = 0; nt < 8; ++nt)
                acc[nt] = MFMA16(Af[nt][kt], Bf[kt], acc[nt]);
        float ssum = 0.f;
        #pragma unroll
        for (int nt = 0; nt < 8; ++nt)
            ssum += acc[nt][0] * e[nt][0] + acc[nt][1] * e[nt][1]
                  + acc[nt][2] * e[nt][2] + acc[nt][3] * e[nt][3];
        if (__ballot(mm <= 0.f)) {
            float os = 0.f;
            #pragma unroll
            for (int p2 = 0; p2 < 16; ++p2) os += lo16f(ps[p2]) + hi16f(ps[p2]);
            ssum = (mm <= 0.f) ? os : ssum;
        }
        ssum += __shfl_xor(ssum, 16, 64);
        ssum += __shfl_xor(ssum, 32, 64);
        if (lane < 16) atomicAdd(&out[g * 16 + lane], __logf(ssum) + lacc);
    }
}

// ---------------------------------------------------------------------------
extern "C" void kernel_launch(void* const* d_in, const int* in_sizes, int n_in,
                              void* d_out, int out_size, void* d_ws, size_t ws_size,
                              hipStream_t stream) {
    (void)in_sizes; (void)n_in; (void)out_size; (void)d_ws; (void)ws_size;
    const float* y_true = (const float*)d_in[0];
    const float* y_pred = (const float*)d_in[1];
    const float* mask   = (const float*)d_in[2];
    const float* trans  = (const float*)d_in[3];
    float* out = (float*)d_out;

    hipMemsetAsync(out, 0, BB * sizeof(float), stream);
    crf_all<<<dim3(8 + BB), 256, 0, stream>>>(y_true, y_pred, mask, trans, out);
}

// Round 6
// 274.430 us; speedup vs baseline: 2.1227x; 2.1227x over previous
//
#include <hip/hip_runtime.h>

#define BB 128
#define TT 512
#define CC 128

typedef short short8 __attribute__((ext_vector_type(8)));
typedef float f32x4  __attribute__((ext_vector_type(4)));
typedef unsigned u32x4 __attribute__((ext_vector_type(4)));
typedef unsigned u32x2 __attribute__((ext_vector_type(2)));

__device__ __forceinline__ unsigned pk_trunc(float a, float b) {
    // lo16 = trunc-bf16(a), hi16 = trunc-bf16(b); single v_perm
    return __builtin_amdgcn_perm(__float_as_uint(a), __float_as_uint(b), 0x03020706u);
}
__device__ __forceinline__ unsigned short f2bf(float f) {   // RNE (A setup only)
    unsigned u = __float_as_uint(f);
    u += 0x7fffu + ((u >> 16) & 1u);
    return (unsigned short)(u >> 16);
}
__device__ __forceinline__ float lo16f(unsigned u) { return __uint_as_float(u << 16); }
__device__ __forceinline__ float hi16f(unsigned u) { return __uint_as_float(u & 0xffff0000u); }

#define MFMA16(A, B, C) __builtin_amdgcn_mfma_f32_16x16x32_bf16((A), (B), (C), 0, 0, 0)

// Build own B-frag block (kt=w) from this wave's nn regs via intra-wave shfl.
// Word j = pair 16w+4q+j. Source: lane (bq,(2q+(j>>1))&3), reg nn[q>>1][j&1].
// (Derivation: pair 16w+8*n2+2*q_src+r = 16w+4q+j -> r=j&1, n2=q>>1,
//  q_src=(2q+(j>>1))&3. Spot-checked q=1 j=0, q=3 j=2, q=2 j=1, q=0 j=3.)
#define BUILD_BFO(n00, n01, n10, n11) do {                                     \
    const int sA_ = bq + 16 * ((2 * q) & 3);                                   \
    const int sB_ = bq + 16 * ((2 * q + 1) & 3);                               \
    unsigned a00 = __shfl((n00), sA_, 64), a10 = __shfl((n10), sA_, 64);       \
    unsigned a01 = __shfl((n01), sA_, 64), a11 = __shfl((n11), sA_, 64);       \
    unsigned b00 = __shfl((n00), sB_, 64), b10 = __shfl((n10), sB_, 64);       \
    unsigned b01 = __shfl((n01), sB_, 64), b11 = __shfl((n11), sB_, 64);       \
    const bool hi_ = (q >> 1) != 0;                                            \
    BfO[0] = hi_ ? a10 : a00;                                                  \
    BfO[1] = hi_ ? a11 : a01;                                                  \
    BfO[2] = hi_ ? b10 : b00;                                                  \
    BfO[3] = hi_ ? b11 : b01;                                                  \
} while (0)

// One scan step (R1-verified semantics; new: own-block shfl-build + stagger +
// split acc + bc via broadcast ds_read_b32).  AP_ at t%4==1: pend from
// state[t-1][0] (read buffer), applied to this step's output, lacc += log.
#define DOSTEP(AP_, P_, RPAR_, TN_) do {                                       \
    const unsigned* sb = &sbuf[RPAR_][0];                                      \
    unsigned* sw = &sbuf[(RPAR_) ^ 1][0];                                      \
    u32x4 Rv1 = *(const u32x4*)(sb + rd1);                                     \
    u32x4 Rv2 = *(const u32x4*)(sb + rd2);                                     \
    u32x4 Rv3 = *(const u32x4*)(sb + rd3);                                     \
    unsigned bcu = 0;                                                          \
    if (AP_) bcu = sb[bcaddr];               /* pair 0 broadcast (ch 0) */     \
    const float mm = pfm[P_];                                                  \
    float e0[4], e1[4];                                                        \
    e0[0] = __expf(pfa[P_].x * mm); e0[1] = __expf(pfa[P_].y * mm);            \
    e0[2] = __expf(pfa[P_].z * mm); e0[3] = __expf(pfa[P_].w * mm);            \
    e1[0] = __expf(pfb[P_].x * mm); e1[1] = __expf(pfb[P_].y * mm);            \
    e1[2] = __expf(pfb[P_].z * mm); e1[3] = __expf(pfb[P_].w * mm);            \
    union { u32x4 u; short8 s; } cO, c1, c2, c3;                               \
    cO.u[0] = BfO[0]; cO.u[1] = BfO[1]; cO.u[2] = BfO[2]; cO.u[3] = BfO[3];    \
    c1.u = Rv1; c2.u = Rv2; c3.u = Rv3;                                        \
    f32x4 aA0 = {0.f,0.f,0.f,0.f}, aA1 = {0.f,0.f,0.f,0.f};                    \
    f32x4 aB0 = {0.f,0.f,0.f,0.f}, aB1 = {0.f,0.f,0.f,0.f};                    \
    aA0 = MFMA16(AfP[0][0], cO.s, aA0);  aA1 = MFMA16(AfP[1][0], cO.s, aA1);   \
    aA0 = MFMA16(AfP[0][1], c1.s, aA0);  aA1 = MFMA16(AfP[1][1], c1.s, aA1);   \
    aB0 = MFMA16(AfP[0][2], c2.s, aB0);  aB1 = MFMA16(AfP[1][2], c2.s, aB1);   \
    aB0 = MFMA16(AfP[0][3], c3.s, aB0);  aB1 = MFMA16(AfP[1][3], c3.s, aB1);   \
    f32x4 ac0 = aA0 + aB0, ac1 = aA1 + aB1;                                    \
    float pend = 1.f;                                                          \
    if (AP_) {                                                                 \
        float bc = lo16f(bcu);                                                 \
        pend = __builtin_amdgcn_rcpf(bc);                                      \
        lacc += __logf(bc);                                                    \
    }                                                                          \
    float v00 = ac0[0]*e0[0], v01 = ac0[1]*e0[1];                              \
    float v02 = ac0[2]*e0[2], v03 = ac0[3]*e0[3];                              \
    float v10 = ac1[0]*e1[0], v11 = ac1[1]*e1[1];                              \
    float v12 = ac1[2]*e1[2], v13 = ac1[3]*e1[3];                              \
    if (AP_) {                                                                 \
        v00 *= pend; v01 *= pend; v02 *= pend; v03 *= pend;                    \
        v10 *= pend; v11 *= pend; v12 *= pend; v13 *= pend;                    \
    }                                                                          \
    unsigned n00 = pk_trunc(v00, v01), n01 = pk_trunc(v02, v03);               \
    unsigned n10 = pk_trunc(v10, v11), n11 = pk_trunc(v12, v13);               \
    if (__ballot(mm <= 0.f)) {               /* rare keep-old (never hit) */   \
        u32x2 o0 = *(const u32x2*)(sb + wwA);                                  \
        u32x2 o1 = *(const u32x2*)(sb + wwB);                                  \
        unsigned k00 = pk_trunc(lo16f(o0[0]) * pend, hi16f(o0[0]) * pend);     \
        unsigned k01 = pk_trunc(lo16f(o0[1]) * pend, hi16f(o0[1]) * pend);     \
        unsigned k10 = pk_trunc(lo16f(o1[0]) * pend, hi16f(o1[0]) * pend);     \
        unsigned k11 = pk_trunc(lo16f(o1[1]) * pend, hi16f(o1[1]) * pend);     \
        const bool kk = (mm <= 0.f);                                           \
        n00 = kk ? k00 : n00; n01 = kk ? k01 : n01;                            \
        n10 = kk ? k10 : n10; n11 = kk ? k11 : n11;                            \
    }                                                                          \
    u32x2 wv0; wv0[0] = n00; wv0[1] = n01;                                     \
    u32x2 wv1; wv1[0] = n10; wv1[1] = n11;                                     \
    *(u32x2*)(sw + wwA) = wv0;                                                 \
    *(u32x2*)(sw + wwB) = wv1;                                                 \
    BUILD_BFO(n00, n01, n10, n11);           /* own block for next step */     \
    if ((TN_) >= 0) {                        /* depth-4 E prefetch */          \
        pfa[P_] = *(const float4*)(yb + (size_t)(TN_) * CC + ch0);             \
        pfb[P_] = *(const float4*)(yb + (size_t)(TN_) * CC + ch0 + 16);        \
        pfm[P_] = mrow[TN_];                                                   \
    }                                                                          \
    asm volatile("s_waitcnt lgkmcnt(0)" ::: "memory");                         \
    __builtin_amdgcn_s_barrier();            /* raw: vm stays in flight */     \
    asm volatile("" ::: "memory");                                             \
} while (0)

// ---------------------------------------------------------------------------
// One fused kernel, 256 threads (4 waves).
// Blocks 0..7  : scan group g, 4 consumer waves; wave w owns output channels
//                [32w,32w+32) (= B-frag block kt=w). Per step: own block built
//                in-register via shfl (MFMA starts at barrier+0), other 3
//                blocks via staggered ds_read_b128; split-acc MFMA chains;
//                pend from broadcast ds_read_b32 of channel 0; one raw
//                s_barrier + lgkmcnt(0) per step (global prefetch in flight).
// Blocks 8..135: real-path score, 4 waves x 128 rows; atomicAdd(-score).
// ---------------------------------------------------------------------------
__global__ __launch_bounds__(256, 1) void crf_all(
    const float* __restrict__ y_true, const float* __restrict__ y_pred,
    const float* __restrict__ mask, const float* __restrict__ trans,
    float* __restrict__ out)
{
    __shared__ __align__(16) unsigned sbuf[2][1024];   // 8 KB double-buffered state
    __shared__ float red[4][16];

    const int tid  = threadIdx.x;
    const int lane = tid & 63;
    const int w    = tid >> 6;

    if (blockIdx.x >= 8) {
        // ===================== real path (verified core, 4x128) =============
        const int rb  = blockIdx.x - 8;
        const int ts  = w * 128;
        const int te  = min(ts + 128, TT - 1);
        const float* yt_b = y_true + (size_t)rb * TT * CC;
        const float* yp_b = y_pred + (size_t)rb * TT * CC;
        const float* m_b  = mask + (size_t)rb * TT;

        float em = 0.f, tr = 0.f;
        int lprev = 0; float mprev = 0.f;
        const float* ytr = yt_b + ts * CC;
        const float* ypr = yp_b + ts * CC;
        float cyt0 = ytr[lane], cyt1 = ytr[lane + 64];
        float cyp0 = ypr[lane], cyp1 = ypr[lane + 64];
        float cm = m_b[ts];
        for (int t = ts; t <= te; ++t) {
            float nyt0 = 0.f, nyt1 = 0.f, nyp0 = 0.f, nyp1 = 0.f, nm = 0.f;
            if (t < te) {
                const float* ytn = yt_b + (t + 1) * CC;
                const float* ypn = yp_b + (t + 1) * CC;
                nyt0 = ytn[lane]; nyt1 = ytn[lane + 64];
                nyp0 = ypn[lane]; nyp1 = ypn[lane + 64];
                nm = m_b[t + 1];
            }
            unsigned long long b0 = __ballot(cyt0 > 0.5f);
            unsigned long long b1 = __ballot(cyt1 > 0.5f);
            int l = b0 ? (__ffsll(b0) - 1) : (64 + __ffsll(b1) - 1);
            float v0 = __shfl(cyp0, l & 63);
            float v1 = __shfl(cyp1, l & 63);
            float v  = (l < 64) ? v0 : v1;
            if (lane == 0) {
                if (t < ts + 128) em += cm * cm * v;
                if (t > ts)       tr += mprev * cm * trans[lprev * CC + l];
            }
            lprev = l; mprev = cm;
            cyt0 = nyt0; cyt1 = nyt1; cyp0 = nyp0; cyp1 = nyp1; cm = nm;
        }
        if (lane == 0) atomicAdd(&out[rb], -(em + tr));
        return;
    }

    // ========================== scan blocks ==========================
    const int bq = lane & 15;
    const int q  = lane >> 4;
    const int g  = blockIdx.x;
    const float* yb   = y_pred + (size_t)(g * 16 + bq) * TT * CC;
    const float* mrow = mask + (size_t)(g * 16 + bq) * TT;
    const int ch0 = 32 * w + 4 * q;          // first channel of this lane's E slice

    // t=0 + depth-4 prefetch issued before A-frag math.
    const float4 i0 = *(const float4*)(yb + ch0);
    const float4 i1 = *(const float4*)(yb + ch0 + 16);
    const float  m0 = mrow[0];
    float4 pfa[4], pfb[4]; float pfm[4];
    #pragma unroll
    for (int p = 0; p < 4; ++p) {
        pfa[p] = *(const float4*)(yb + (size_t)(1 + p) * CC + ch0);
        pfb[p] = *(const float4*)(yb + (size_t)(1 + p) * CC + ch0 + 16);
        pfm[p] = mrow[1 + p];
    }

    // A-frags, stagger-permuted: AfP[n2][i] = block kt=(w+i)&3, output rows
    // j = (2w+n2)*16 + bq, k = kt*32 + 8q + e   (R1-verified mapping).
    short8 AfP[2][4];
    #pragma unroll
    for (int n2 = 0; n2 < 2; ++n2) {
        const int j = (2 * w + n2) * 16 + bq;
        #pragma unroll
        for (int i = 0; i < 4; ++i) {
            const int kt = (w + i) & 3;
            #pragma unroll
            for (int e = 0; e < 8; ++e)
                AfP[n2][i][e] = (short)f2bf(__expf(trans[(kt * 32 + q * 8 + e) * CC + j]));
        }
    }

    // LDS layout (R1-verified): col bq at 64 words; pair P at word (P ^ swz),
    // swz = (bq&7)<<2. Stagger reads: block kt=(w+i)&3 at word kt*16+4q (^swz).
    const int swz = (bq & 7) << 2;
    const int rd1 = bq * 64 + ((((w + 1) & 3) * 16 + 4 * q) ^ swz);
    const int rd2 = bq * 64 + ((((w + 2) & 3) * 16 + 4 * q) ^ swz);
    const int rd3 = bq * 64 + ((((w + 3) & 3) * 16 + 4 * q) ^ swz);
    const int wwA = bq * 64 + ((16 * w + 2 * q) ^ swz);      // pairs 16w+2q,+1
    const int wwB = bq * 64 + ((16 * w + 8 + 2 * q) ^ swz);  // pairs 16w+8+2q,+1
    const int bcaddr = bq * 64 + swz;                        // pair 0 (channel 0)

    unsigned BfO[4];                         // own block kt=w, in registers

    // t=0 init: state = exp(y_pred[:,0,:] * m0); write slice + build own block.
    {
        unsigned n00 = pk_trunc(__expf(i0.x * m0), __expf(i0.y * m0));
        unsigned n01 = pk_trunc(__expf(i0.z * m0), __expf(i0.w * m0));
        unsigned n10 = pk_trunc(__expf(i1.x * m0), __expf(i1.y * m0));
        unsigned n11 = pk_trunc(__expf(i1.z * m0), __expf(i1.w * m0));
        u32x2 a; a[0] = n00; a[1] = n01;
        u32x2 b; b[0] = n10; b[1] = n11;
        *(u32x2*)(&sbuf[0][0] + wwA) = a;
        *(u32x2*)(&sbuf[0][0] + wwB) = b;
        BUILD_BFO(n00, n01, n10, n11);
    }
    asm volatile("s_waitcnt lgkmcnt(0)" ::: "memory");
    __builtin_amdgcn_s_barrier();
    asm volatile("" ::: "memory");

    float lacc = 0.f;

    // steps 1..508 (127 chunks of 4; AP at t%4==1)
    for (int tt = 1; tt <= 505; tt += 4) {
        int t4 = tt + 4, t5 = tt + 5, t6 = tt + 6, t7 = tt + 7;
        if (t7 > TT - 1) t7 = TT - 1;        // only tt=505 clamps (512 -> 511)
        DOSTEP(true,  0, 0, t4);
        DOSTEP(false, 1, 1, t5);
        DOSTEP(false, 2, 0, t6);
        DOSTEP(false, 3, 1, t7);
    }
    // steps 509 (AP), 510
    DOSTEP(true,  0, 0, -1);
    DOSTEP(false, 1, 1, -1);

    // -------- step 511: final partial sum (pend == 1; reads buf 0) ----------
    {
        const unsigned* sb = &sbuf[0][0];
        u32x4 Rv1 = *(const u32x4*)(sb + rd1);
        u32x4 Rv2 = *(const u32x4*)(sb + rd2);
        u32x4 Rv3 = *(const u32x4*)(sb + rd3);
        const float mm = pfm[2];             // slot 2 holds t=511
        float e0[4], e1[4];
        e0[0] = __expf(pfa[2].x * mm); e0[1] = __expf(pfa[2].y * mm);
        e0[2] = __expf(pfa[2].z * mm); e0[3] = __expf(pfa[2].w * mm);
        e1[0] = __expf(pfb[2].x * mm); e1[1] = __expf(pfb[2].y * mm);
        e1[2] = __expf(pfb[2].z * mm); e1[3] = __expf(pfb[2].w * mm);
        union { u32x4 u; short8 s; } cO, c1, c2, c3;
        cO.u[0] = BfO[0]; cO.u[1] = BfO[1]; cO.u[2] = BfO[2]; cO.u[3] = BfO[3];
        c1.u = Rv1; c2.u = Rv2; c3.u = Rv3;
        f32x4 aA0 = {0.f,0.f,0.f,0.f}, aA1 = {0.f,0.f,0.f,0.f};
        f32x4 aB0 = {0.f,0.f,0.f,0.f}, aB1 = {0.f,0.f,0.f,0.f};
        aA0 = MFMA16(AfP[0][0], cO.s, aA0);  aA1 = MFMA16(AfP[1][0], cO.s, aA1);
        aA0 = MFMA16(AfP[0][1], c1.s, aA0);  aA1 = MFMA16(AfP[1][1], c1.s, aA1);
        aB0 = MFMA16(AfP[0][2], c2.s, aB0);  aB1 = MFMA16(AfP[1][2], c2.s, aB1);
        aB0 = MFMA16(AfP[0][3], c3.s, aB0);  aB1 = MFMA16(AfP[1][3], c3.s, aB1);
        f32x4 ac0 = aA0 + aB0, ac1 = aA1 + aB1;
        float ssum = ac0[0]*e0[0] + ac0[1]*e0[1] + ac0[2]*e0[2] + ac0[3]*e0[3]
                   + ac1[0]*e1[0] + ac1[1]*e1[1] + ac1[2]*e1[2] + ac1[3]*e1[3];
        if (__ballot(mm <= 0.f)) {           // pend == 1 here (511 % 4 == 3)
            u32x2 o0 = *(const u32x2*)(sb + wwA);
            u32x2 o1 = *(const u32x2*)(sb + wwB);
            float os = lo16f(o0[0]) + hi16f(o0[0]) + lo16f(o0[1]) + hi16f(o0[1])
                     + lo16f(o1[0]) + hi16f(o1[0]) + lo16f(o1[1]) + hi16f(o1[1]);
            ssum = (mm <= 0.f) ? os : ssum;
        }
        ssum += __shfl_xor(ssum, 16, 64);
        ssum += __shfl_xor(ssum, 32, 64);
        if (lane < 16) red[w][lane] = ssum;
        asm volatile("s_waitcnt lgkmcnt(0)" ::: "memory");
        __builtin_amdgcn_s_barrier();
        asm volatile("" ::: "memory");
        if (w == 0 && lane < 16) {
            float tot = red[0][lane] + red[1][lane] + red[2][lane] + red[3][lane];
            atomicAdd(&out[g * 16 + lane], __logf(tot) + lacc);
        }
    }
}

// ---------------------------------------------------------------------------
extern "C" void kernel_launch(void* const* d_in, const int* in_sizes, int n_in,
                              void* d_out, int out_size, void* d_ws, size_t ws_size,
                              hipStream_t stream) {
    (void)in_sizes; (void)n_in; (void)out_size; (void)d_ws; (void)ws_size;
    const float* y_true = (const float*)d_in[0];
    const float* y_pred = (const float*)d_in[1];
    const float* mask   = (const float*)d_in[2];
    const float* trans  = (const float*)d_in[3];
    float* out = (float*)d_out;

    hipMemsetAsync(out, 0, BB * sizeof(float), stream);
    crf_all<<<dim3(8 + BB), 256, 0, stream>>>(y_true, y_pred, mask, trans, out);
}

// Round 7
// 253.812 us; speedup vs baseline: 2.2951x; 1.0812x over previous
//
#include <hip/hip_runtime.h>

#define BB 128
#define TT 512
#define CC 128

typedef short short8 __attribute__((ext_vector_type(8)));
typedef float f32x4  __attribute__((ext_vector_type(4)));
typedef unsigned u32x4 __attribute__((ext_vector_type(4)));

__device__ __forceinline__ unsigned pk_trunc(float a, float b) {
    // lo16 = trunc-bf16(a), hi16 = trunc-bf16(b); single v_perm
    return __builtin_amdgcn_perm(__float_as_uint(a), __float_as_uint(b), 0x03020706u);
}
__device__ __forceinline__ unsigned short f2bf(float f) {   // RNE (A setup only)
    unsigned u = __float_as_uint(f);
    u += 0x7fffu + ((u >> 16) & 1u);
    return (unsigned short)(u >> 16);
}
__device__ __forceinline__ float lo16f(unsigned u) { return __uint_as_float(u << 16); }
__device__ __forceinline__ float hi16f(unsigned u) { return __uint_as_float(u & 0xffff0000u); }

#define MFMA16(A, B, C) __builtin_amdgcn_mfma_f32_16x16x32_bf16((A), (B), (C), 0, 0, 0)

// One scan step. sigma'-permuted A (R4-verified family): lane (bq,q) outputs
// channels 32w+8q+{0..7} = pairs 16w+4q+{0..3} = its OWN next-step B-frag
// block kt=w -> own block stays in BfO regs (no LDS read, no shfl), write is
// ONE b128 at the conflict-free (16w+4q)^swz pattern, keep-old uses BfO.
// AP_ at t%4==1: pend from broadcast read of channel 0 (R6-verified bcaddr).
#define DOSTEP(AP_, P_, RPAR_, TN_) do {                                       \
    const unsigned* sb = &sbuf[RPAR_][0];                                      \
    unsigned* sw = &sbuf[(RPAR_) ^ 1][0];                                      \
    u32x4 Rv1 = *(const u32x4*)(sb + rd1);                                     \
    u32x4 Rv2 = *(const u32x4*)(sb + rd2);                                     \
    u32x4 Rv3 = *(const u32x4*)(sb + rd3);                                     \
    unsigned bcu = 0;                                                          \
    if (AP_) bcu = sb[bcaddr];               /* pair 0 broadcast (ch 0) */     \
    const float mm = pfm[P_];                                                  \
    float e0[4], e1[4];                                                        \
    e0[0] = __expf(pfa[P_].x * mm); e0[1] = __expf(pfa[P_].y * mm);            \
    e0[2] = __expf(pfa[P_].z * mm); e0[3] = __expf(pfa[P_].w * mm);            \
    e1[0] = __expf(pfb[P_].x * mm); e1[1] = __expf(pfb[P_].y * mm);            \
    e1[2] = __expf(pfb[P_].z * mm); e1[3] = __expf(pfb[P_].w * mm);            \
    union { u32x4 u; short8 s; } cO, c1, c2, c3;                               \
    cO.u[0] = BfO[0]; cO.u[1] = BfO[1]; cO.u[2] = BfO[2]; cO.u[3] = BfO[3];    \
    c1.u = Rv1; c2.u = Rv2; c3.u = Rv3;                                        \
    f32x4 aA0 = {0.f,0.f,0.f,0.f}, aA1 = {0.f,0.f,0.f,0.f};                    \
    f32x4 aB0 = {0.f,0.f,0.f,0.f}, aB1 = {0.f,0.f,0.f,0.f};                    \
    aA0 = MFMA16(AfP[0][0], cO.s, aA0);  aA1 = MFMA16(AfP[1][0], cO.s, aA1);   \
    aA0 = MFMA16(AfP[0][1], c1.s, aA0);  aA1 = MFMA16(AfP[1][1], c1.s, aA1);   \
    aB0 = MFMA16(AfP[0][2], c2.s, aB0);  aB1 = MFMA16(AfP[1][2], c2.s, aB1);   \
    aB0 = MFMA16(AfP[0][3], c3.s, aB0);  aB1 = MFMA16(AfP[1][3], c3.s, aB1);   \
    f32x4 ac0 = aA0 + aB0, ac1 = aA1 + aB1;                                    \
    float pend = 1.f;                                                          \
    if (AP_) {                                                                 \
        float bc = lo16f(bcu);                                                 \
        pend = __builtin_amdgcn_rcpf(bc);                                      \
        lacc += __logf(bc);                                                    \
    }                                                                          \
    float v00 = ac0[0]*e0[0], v01 = ac0[1]*e0[1];                              \
    float v02 = ac0[2]*e0[2], v03 = ac0[3]*e0[3];                              \
    float v10 = ac1[0]*e1[0], v11 = ac1[1]*e1[1];                              \
    float v12 = ac1[2]*e1[2], v13 = ac1[3]*e1[3];                              \
    if (AP_) {                                                                 \
        v00 *= pend; v01 *= pend; v02 *= pend; v03 *= pend;                    \
        v10 *= pend; v11 *= pend; v12 *= pend; v13 *= pend;                    \
    }                                                                          \
    unsigned n0 = pk_trunc(v00, v01), n1 = pk_trunc(v02, v03);                 \
    unsigned n2 = pk_trunc(v10, v11), n3 = pk_trunc(v12, v13);                 \
    if (__ballot(mm <= 0.f)) {               /* rare keep-old (never hit) */   \
        unsigned k0 = pk_trunc(lo16f(BfO[0]) * pend, hi16f(BfO[0]) * pend);    \
        unsigned k1 = pk_trunc(lo16f(BfO[1]) * pend, hi16f(BfO[1]) * pend);    \
        unsigned k2 = pk_trunc(lo16f(BfO[2]) * pend, hi16f(BfO[2]) * pend);    \
        unsigned k3 = pk_trunc(lo16f(BfO[3]) * pend, hi16f(BfO[3]) * pend);    \
        const bool kk = (mm <= 0.f);                                           \
        n0 = kk ? k0 : n0; n1 = kk ? k1 : n1;                                  \
        n2 = kk ? k2 : n2; n3 = kk ? k3 : n3;                                  \
    }                                                                          \
    u32x4 wv; wv[0] = n0; wv[1] = n1; wv[2] = n2; wv[3] = n3;                  \
    *(u32x4*)(sw + wwOwn) = wv;              /* one b128, conflict-free */     \
    BfO[0] = n0; BfO[1] = n1; BfO[2] = n2; BfO[3] = n3;                        \
    if ((TN_) >= 0) {                        /* depth-4 E prefetch */          \
        pfa[P_] = *(const float4*)(yb + (size_t)(TN_) * CC + ch0p);            \
        pfb[P_] = *(const float4*)(yb + (size_t)(TN_) * CC + ch0p + 4);        \
        pfm[P_] = mrow[TN_];                                                   \
    }                                                                          \
    asm volatile("s_waitcnt lgkmcnt(0)" ::: "memory");                         \
    __builtin_amdgcn_s_barrier();            /* raw: vm stays in flight */     \
    asm volatile("" ::: "memory");                                             \
} while (0)

// ---------------------------------------------------------------------------
// One fused kernel, 256 threads (4 waves).
// Blocks 0..7  : scan group g, 4 consumer waves; wave w owns channels
//                [32w,32w+32). sigma'-permuted A makes each lane's outputs its
//                own next-step B-frag (register-resident own block); other 3
//                blocks via staggered conflict-free ds_read_b128; one b128
//                write; one raw s_barrier + lgkmcnt(0)/step (vm in flight).
// Blocks 8..135: real-path score, 4 waves x 128 rows; atomicAdd(-score).
// R6 lesson: __shfl is LDS-pipe traffic — layout, not shuffles, must deliver
// the own block to registers.
// ---------------------------------------------------------------------------
__global__ __launch_bounds__(256, 1) void crf_all(
    const float* __restrict__ y_true, const float* __restrict__ y_pred,
    const float* __restrict__ mask, const float* __restrict__ trans,
    float* __restrict__ out)
{
    __shared__ __align__(16) unsigned sbuf[2][1024];   // 8 KB double-buffered state
    __shared__ float red[4][16];

    const int tid  = threadIdx.x;
    const int lane = tid & 63;
    const int w    = tid >> 6;

    if (blockIdx.x >= 8) {
        // ===================== real path (verified core, 4x128) =============
        const int rb  = blockIdx.x - 8;
        const int ts  = w * 128;
        const int te  = min(ts + 128, TT - 1);
        const float* yt_b = y_true + (size_t)rb * TT * CC;
        const float* yp_b = y_pred + (size_t)rb * TT * CC;
        const float* m_b  = mask + (size_t)rb * TT;

        float em = 0.f, tr = 0.f;
        int lprev = 0; float mprev = 0.f;
        const float* ytr = yt_b + ts * CC;
        const float* ypr = yp_b + ts * CC;
        float cyt0 = ytr[lane], cyt1 = ytr[lane + 64];
        float cyp0 = ypr[lane], cyp1 = ypr[lane + 64];
        float cm = m_b[ts];
        for (int t = ts; t <= te; ++t) {
            float nyt0 = 0.f, nyt1 = 0.f, nyp0 = 0.f, nyp1 = 0.f, nm = 0.f;
            if (t < te) {
                const float* ytn = yt_b + (t + 1) * CC;
                const float* ypn = yp_b + (t + 1) * CC;
                nyt0 = ytn[lane]; nyt1 = ytn[lane + 64];
                nyp0 = ypn[lane]; nyp1 = ypn[lane + 64];
                nm = m_b[t + 1];
            }
            unsigned long long b0 = __ballot(cyt0 > 0.5f);
            unsigned long long b1 = __ballot(cyt1 > 0.5f);
            int l = b0 ? (__ffsll(b0) - 1) : (64 + __ffsll(b1) - 1);
            float v0 = __shfl(cyp0, l & 63);
            float v1 = __shfl(cyp1, l & 63);
            float v  = (l < 64) ? v0 : v1;
            if (lane == 0) {
                if (t < ts + 128) em += cm * cm * v;
                if (t > ts)       tr += mprev * cm * trans[lprev * CC + l];
            }
            lprev = l; mprev = cm;
            cyt0 = nyt0; cyt1 = nyt1; cyp0 = nyp0; cyp1 = nyp1; cm = nm;
        }
        if (lane == 0) atomicAdd(&out[rb], -(em + tr));
        return;
    }

    // ========================== scan blocks ==========================
    const int bq = lane & 15;
    const int q  = lane >> 4;
    const int g  = blockIdx.x;
    const float* yb   = y_pred + (size_t)(g * 16 + bq) * TT * CC;
    const float* mrow = mask + (size_t)(g * 16 + bq) * TT;
    const int ch0p = 32 * w + 8 * q;         // lane's 8 channels: ch0p..ch0p+7

    // t=0 + depth-4 prefetch issued before A-frag math.
    const float4 i0 = *(const float4*)(yb + ch0p);
    const float4 i1 = *(const float4*)(yb + ch0p + 4);
    const float  m0 = mrow[0];
    float4 pfa[4], pfb[4]; float pfm[4];
    #pragma unroll
    for (int p = 0; p < 4; ++p) {
        pfa[p] = *(const float4*)(yb + (size_t)(1 + p) * CC + ch0p);
        pfb[p] = *(const float4*)(yb + (size_t)(1 + p) * CC + ch0p + 4);
        pfm[p] = mrow[1 + p];
    }

    // A-frags, sigma'-permuted + stagger: AfP[n2][i] = block kt=(w+i)&3,
    // A[row=bq][k=kt*32+8q+e] = expT[k][j], j = 32w + 8*(bq>>2) + 4*n2 + (bq&3).
    // => lane (bq,q) outputs channels 32w+8q+4*n2+r (r=acc reg) — its own
    //    next-step B-frag pairs 16w+4q+{0..3}. (sigma verified R0/R4.)
    short8 AfP[2][4];
    #pragma unroll
    for (int n2 = 0; n2 < 2; ++n2) {
        const int j = 32 * w + 8 * (bq >> 2) + 4 * n2 + (bq & 3);
        #pragma unroll
        for (int i = 0; i < 4; ++i) {
            const int kt = (w + i) & 3;
            #pragma unroll
            for (int e = 0; e < 8; ++e)
                AfP[n2][i][e] = (short)f2bf(__expf(trans[(kt * 32 + q * 8 + e) * CC + j]));
        }
    }

    // LDS layout (R1-verified): col bq at 64 words; pair P at word (P ^ swz),
    // swz = (bq&7)<<2. All accesses b128 at (16*kt+4q)^swz: 8 words/bank.
    const int swz = (bq & 7) << 2;
    const int rd1 = bq * 64 + ((((w + 1) & 3) * 16 + 4 * q) ^ swz);
    const int rd2 = bq * 64 + ((((w + 2) & 3) * 16 + 4 * q) ^ swz);
    const int rd3 = bq * 64 + ((((w + 3) & 3) * 16 + 4 * q) ^ swz);
    const int wwOwn = bq * 64 + ((16 * w + 4 * q) ^ swz);    // pairs 16w+4q..+3
    const int bcaddr = bq * 64 + swz;                        // pair 0 (channel 0)

    unsigned BfO[4];                         // own block kt=w (= lane's pairs)

    // t=0 init: state = exp(y_pred[:,0,:] * m0); lane packs its own 4 pairs.
    {
        unsigned n0 = pk_trunc(__expf(i0.x * m0), __expf(i0.y * m0));
        unsigned n1 = pk_trunc(__expf(i0.z * m0), __expf(i0.w * m0));
        unsigned n2 = pk_trunc(__expf(i1.x * m0), __expf(i1.y * m0));
        unsigned n3 = pk_trunc(__expf(i1.z * m0), __expf(i1.w * m0));
        u32x4 wv; wv[0] = n0; wv[1] = n1; wv[2] = n2; wv[3] = n3;
        *(u32x4*)(&sbuf[0][0] + wwOwn) = wv;
        BfO[0] = n0; BfO[1] = n1; BfO[2] = n2; BfO[3] = n3;
    }
    asm volatile("s_waitcnt lgkmcnt(0)" ::: "memory");
    __builtin_amdgcn_s_barrier();
    asm volatile("" ::: "memory");

    float lacc = 0.f;

    // steps 1..508 (127 chunks of 4; AP at t%4==1)
    for (int tt = 1; tt <= 505; tt += 4) {
        int t4 = tt + 4, t5 = tt + 5, t6 = tt + 6, t7 = tt + 7;
        if (t7 > TT - 1) t7 = TT - 1;        // only tt=505 clamps (512 -> 511)
        DOSTEP(true,  0, 0, t4);
        DOSTEP(false, 1, 1, t5);
        DOSTEP(false, 2, 0, t6);
        DOSTEP(false, 3, 1, t7);
    }
    // steps 509 (AP), 510
    DOSTEP(true,  0, 0, -1);
    DOSTEP(false, 1, 1, -1);

    // -------- step 511: final partial sum (pend == 1; reads buf 0) ----------
    {
        const unsigned* sb = &sbuf[0][0];
        u32x4 Rv1 = *(const u32x4*)(sb + rd1);
        u32x4 Rv2 = *(const u32x4*)(sb + rd2);
        u32x4 Rv3 = *(const u32x4*)(sb + rd3);
        const float mm = pfm[2];             // slot 2 holds t=511
        float e0[4], e1[4];
        e0[0] = __expf(pfa[2].x * mm); e0[1] = __expf(pfa[2].y * mm);
        e0[2] = __expf(pfa[2].z * mm); e0[3] = __expf(pfa[2].w * mm);
        e1[0] = __expf(pfb[2].x * mm); e1[1] = __expf(pfb[2].y * mm);
        e1[2] = __expf(pfb[2].z * mm); e1[3] = __expf(pfb[2].w * mm);
        union { u32x4 u; short8 s; } cO, c1, c2, c3;
        cO.u[0] = BfO[0]; cO.u[1] = BfO[1]; cO.u[2] = BfO[2]; cO.u[3] = BfO[3];
        c1.u = Rv1; c2.u = Rv2; c3.u = Rv3;
        f32x4 aA0 = {0.f,0.f,0.f,0.f}, aA1 = {0.f,0.f,0.f,0.f};
        f32x4 aB0 = {0.f,0.f,0.f,0.f}, aB1 = {0.f,0.f,0.f,0.f};
        aA0 = MFMA16(AfP[0][0], cO.s, aA0);  aA1 = MFMA16(AfP[1][0], cO.s, aA1);
        aA0 = MFMA16(AfP[0][1], c1.s, aA0);  aA1 = MFMA16(AfP[1][1], c1.s, aA1);
        aB0 = MFMA16(AfP[0][2], c2.s, aB0);  aB1 = MFMA16(AfP[1][2], c2.s, aB1);
        aB0 = MFMA16(AfP[0][3], c3.s, aB0);  aB1 = MFMA16(AfP[1][3], c3.s, aB1);
        f32x4 ac0 = aA0 + aB0, ac1 = aA1 + aB1;
        float ssum = ac0[0]*e0[0] + ac0[1]*e0[1] + ac0[2]*e0[2] + ac0[3]*e0[3]
                   + ac1[0]*e1[0] + ac1[1]*e1[1] + ac1[2]*e1[2] + ac1[3]*e1[3];
        if (__ballot(mm <= 0.f)) {           // pend == 1 here (511 % 4 == 3)
            float os = lo16f(BfO[0]) + hi16f(BfO[0]) + lo16f(BfO[1]) + hi16f(BfO[1])
                     + lo16f(BfO[2]) + hi16f(BfO[2]) + lo16f(BfO[3]) + hi16f(BfO[3]);
            ssum = (mm <= 0.f) ? os : ssum;
        }
        ssum += __shfl_xor(ssum, 16, 64);
        ssum += __shfl_xor(ssum, 32, 64);
        if (lane < 16) red[w][lane] = ssum;
        asm volatile("s_waitcnt lgkmcnt(0)" ::: "memory");
        __builtin_amdgcn_s_barrier();
        asm volatile("" ::: "memory");
        if (w == 0 && lane < 16) {
            float tot = red[0][lane] + red[1][lane] + red[2][lane] + red[3][lane];
            atomicAdd(&out[g * 16 + lane], __logf(tot) + lacc);
        }
    }
}

// ---------------------------------------------------------------------------
extern "C" void kernel_launch(void* const* d_in, const int* in_sizes, int n_in,
                              void* d_out, int out_size, void* d_ws, size_t ws_size,
                              hipStream_t stream) {
    (void)in_sizes; (void)n_in; (void)out_size; (void)d_ws; (void)ws_size;
    const float* y_true = (const float*)d_in[0];
    const float* y_pred = (const float*)d_in[1];
    const float* mask   = (const float*)d_in[2];
    const float* trans  = (const float*)d_in[3];
    float* out = (float*)d_out;

    hipMemsetAsync(out, 0, BB * sizeof(float), stream);
    crf_all<<<dim3(8 + BB), 256, 0, stream>>>(y_true, y_pred, mask, trans, out);
}